// Round 2
// baseline (132.581 us; speedup 1.0000x reference)
//
#include <hip/hip_runtime.h>
#include <hip/hip_bf16.h>

#define S 1024
#define C 384
#define NC 32
#define SHIFT 0.3f

typedef __attribute__((ext_vector_type(4))) float f32x4;
typedef __attribute__((ext_vector_type(8))) short short8;

// f32 -> bf16 (round-to-nearest-even), raw-bit version (finite inputs only)
__device__ __forceinline__ unsigned int f2bf(float x) {
  unsigned int u = __builtin_bit_cast(unsigned int, x);
  unsigned int rb = ((u >> 16) & 1u) + 0x7fffu;
  return (u + rb) >> 16;
}
__device__ __forceinline__ unsigned int f2bf2(float lo, float hi) {
  return f2bf(lo) | (f2bf(hi) << 16);
}

// ---- 1/max(||f_row||,eps) for each of the 4096 feat rows; one wave per row ----
__global__ __launch_bounds__(256) void k_invnorm(const float* __restrict__ f,
                                                 float* __restrict__ invn) {
  int lane = threadIdx.x & 63;
  int row = blockIdx.x * 4 + (threadIdx.x >> 6);
  const float* fr = f + (size_t)row * C;
  float ss = 0.f;
#pragma unroll
  for (int i = 0; i < C / 64; ++i) {
    float v = fr[lane + i * 64];
    ss = fmaf(v, v, ss);
  }
#pragma unroll
  for (int m = 32; m >= 1; m >>= 1) ss += __shfl_xor(ss, m, 64);
  if (lane == 0) invn[row] = 1.f / fmaxf(sqrtf(ss), 1e-12f);
}

// ---- rowdot[r] = sum_c exp(p_rc)*p_rc ; block 0 zeroes the accumulators ----
__global__ __launch_bounds__(256) void k_rowdot(const float* __restrict__ p,
                                                float* __restrict__ rowdot,
                                                float* __restrict__ accum) {
  int row = blockIdx.x * 8 + (threadIdx.x >> 5);
  int c = threadIdx.x & 31;
  float v = p[(size_t)row * NC + c];
  float t = __expf(v) * v;
#pragma unroll
  for (int m = 16; m >= 1; m >>= 1) t += __shfl_xor(t, m, 64);
  if (c == 0) rowdot[row] = t;
  if (blockIdx.x == 0 && threadIdx.x < 8) accum[threadIdx.x] = 0.f;
}

// ---- fused pairwise kernel: 128x128 tile per block, both GEMMs via bf16 MFMA ----
__global__ __launch_bounds__(256, 1) void k_pair(
    const float* __restrict__ f, const float* __restrict__ p,
    const float* __restrict__ invn, const float* __restrict__ rowdot,
    float* __restrict__ accum) {
  __shared__ unsigned short As[128 * 64];  // bf16 fn tile (s rows)
  __shared__ unsigned short Bs[128 * 64];  // bf16 fn tile (l rows)
  __shared__ unsigned short Es[128 * 32];  // bf16 exp(p) rows (s)
  __shared__ unsigned short Ps[128 * 32];  // bf16 p rows (l)

  const int tid = threadIdx.x;
  const int lane = tid & 63;
  const int wave = tid >> 6;
  const int wy = wave >> 1, wx = wave & 1;
  const int lan = lane & 15, quad = lane >> 4;
  const int n = blockIdx.z;
  const int sBase = blockIdx.y * 128;
  const int lBase = blockIdx.x * 128;

  const float* fA = f + (size_t)(n * S + sBase) * C;
  const float* fB = f + (size_t)(n * S + lBase) * C;
  const float* pS = p + (size_t)(n * S + sBase) * NC;
  const float* pL = p + (size_t)(n * S + lBase) * NC;
  const float* invA = invn + n * S + sBase;
  const float* invB = invn + n * S + lBase;

  f32x4 acc[4][4];
#pragma unroll
  for (int i = 0; i < 4; ++i)
#pragma unroll
    for (int j = 0; j < 4; ++j) acc[i][j] = (f32x4){0.f, 0.f, 0.f, 0.f};

  // stage E = bf16(exp(p_s)) and P = bf16(p_l); covered by first barrier below
#pragma unroll
  for (int it = 0; it < 4; ++it) {
    int idx = tid + it * 256;
    int row = idx >> 3, c4 = idx & 7;
    float4 v = *(const float4*)(pS + row * NC + c4 * 4);
    uint2 ue;
    ue.x = f2bf2(__expf(v.x), __expf(v.y));
    ue.y = f2bf2(__expf(v.z), __expf(v.w));
    *(uint2*)(&Es[row * 32 + c4 * 4]) = ue;
    float4 w = *(const float4*)(pL + row * NC + c4 * 4);
    uint2 up;
    up.x = f2bf2(w.x, w.y);
    up.y = f2bf2(w.z, w.w);
    *(uint2*)(&Ps[row * 32 + c4 * 4]) = up;
  }

  // K loop: 6 chunks of BK=64 over C=384
  for (int kt = 0; kt < 6; ++kt) {
#pragma unroll
    for (int it = 0; it < 8; ++it) {
      int idx = tid + it * 256;
      int row = idx >> 4, c4 = idx & 15;
      float4 a = *(const float4*)(fA + row * C + kt * 64 + c4 * 4);
      float sa = invA[row];
      uint2 ua;
      ua.x = f2bf2(a.x * sa, a.y * sa);
      ua.y = f2bf2(a.z * sa, a.w * sa);
      *(uint2*)(&As[row * 64 + c4 * 4]) = ua;
      float4 b = *(const float4*)(fB + row * C + kt * 64 + c4 * 4);
      float sb = invB[row];
      uint2 ub;
      ub.x = f2bf2(b.x * sb, b.y * sb);
      ub.y = f2bf2(b.z * sb, b.w * sb);
      *(uint2*)(&Bs[row * 64 + c4 * 4]) = ub;
    }
    __syncthreads();
#pragma unroll
    for (int ks = 0; ks < 2; ++ks) {
      short8 af[4], bfr[4];
#pragma unroll
      for (int t = 0; t < 4; ++t)
        af[t] = *(const short8*)(&As[(wy * 64 + t * 16 + lan) * 64 + ks * 32 + quad * 8]);
#pragma unroll
      for (int t = 0; t < 4; ++t)
        bfr[t] = *(const short8*)(&Bs[(wx * 64 + t * 16 + lan) * 64 + ks * 32 + quad * 8]);
#pragma unroll
      for (int i = 0; i < 4; ++i)
#pragma unroll
        for (int j = 0; j < 4; ++j)
          acc[i][j] = __builtin_amdgcn_mfma_f32_16x16x32_bf16(af[i], bfr[j], acc[i][j], 0, 0, 0);
    }
    __syncthreads();  // safe to overwrite As/Bs next iteration
  }

  // EP mini-GEMM: one 16x16x32 MFMA per (i,j) tile (K = NC = 32 exactly)
  f32x4 ep[4][4];
  short8 ea[4], pb[4];
#pragma unroll
  for (int t = 0; t < 4; ++t) {
    ea[t] = *(const short8*)(&Es[(wy * 64 + t * 16 + lan) * 32 + quad * 8]);
    pb[t] = *(const short8*)(&Ps[(wx * 64 + t * 16 + lan) * 32 + quad * 8]);
  }
#pragma unroll
  for (int i = 0; i < 4; ++i)
#pragma unroll
    for (int j = 0; j < 4; ++j) {
      f32x4 z = (f32x4){0.f, 0.f, 0.f, 0.f};
      ep[i][j] = __builtin_amdgcn_mfma_f32_16x16x32_bf16(ea[i], pb[j], z, 0, 0, 0);
    }

  // epilogue: C/D layout col=lane&15, row=quad*4+reg
  float pos_s = 0.f, neg_s = 0.f, posc = 0.f, negc = 0.f;
#pragma unroll
  for (int i = 0; i < 4; ++i) {
    float rd[4];
    int gs = n * S + sBase + wy * 64 + i * 16 + quad * 4;
#pragma unroll
    for (int r = 0; r < 4; ++r) rd[r] = rowdot[gs + r];
#pragma unroll
    for (int j = 0; j < 4; ++j) {
#pragma unroll
      for (int r = 0; r < 4; ++r) {
        float fc = acc[i][j][r] - SHIFT;
        float pc = rd[r] - ep[i][j][r];
        if (fc > 0.f) {
          pos_s = fmaf(fc, pc, pos_s);
          posc += 1.f;
        } else if (fc < 0.f) {
          neg_s = fmaf(fc, pc, neg_s);
          negc += 1.f;
        }
      }
    }
  }
#pragma unroll
  for (int m = 32; m >= 1; m >>= 1) {
    pos_s += __shfl_xor(pos_s, m, 64);
    neg_s += __shfl_xor(neg_s, m, 64);
    posc += __shfl_xor(posc, m, 64);
    negc += __shfl_xor(negc, m, 64);
  }
  if (lane == 0) {
    atomicAdd(&accum[0], pos_s);
    atomicAdd(&accum[1], neg_s);
    atomicAdd(&accum[2], posc);
    atomicAdd(&accum[3], negc);
  }
}

__global__ void k_final(const float* __restrict__ accum, float* __restrict__ out) {
  if (threadIdx.x == 0) {
    out[0] = accum[0] / accum[2];
    out[1] = accum[1] / accum[3];
  }
}

extern "C" void kernel_launch(void* const* d_in, const int* in_sizes, int n_in,
                              void* d_out, int out_size, void* d_ws, size_t ws_size,
                              hipStream_t stream) {
  const float* f = (const float*)d_in[0];  // feats [4,32,32,384] f32
  const float* p = (const float*)d_in[1];  // p_class [4,32,32,32] f32 (log-probs)
  float* out = (float*)d_out;              // [pos, neg]
  float* ws = (float*)d_ws;
  float* invn = ws;            // 4096 floats
  float* rowdot = ws + 4096;   // 4096 floats
  float* accum = ws + 8192;    // 8 floats (pos_s, neg_s, posc, negc, pad)

  k_invnorm<<<dim3(1024), dim3(256), 0, stream>>>(f, invn);
  k_rowdot<<<dim3(512), dim3(256), 0, stream>>>(p, rowdot, accum);
  k_pair<<<dim3(8, 8, 4), dim3(256), 0, stream>>>(f, p, invn, rowdot, accum);
  k_final<<<dim3(1), dim3(64), 0, stream>>>(accum, out);
}

// Round 3
// 80.426 us; speedup vs baseline: 1.6485x; 1.6485x over previous
//
#include <hip/hip_runtime.h>
#include <hip/hip_bf16.h>

#define S 1024
#define C 384
#define NC 32
#define SHIFT 0.3f

typedef __attribute__((ext_vector_type(4))) float f32x4;
typedef __attribute__((ext_vector_type(8))) short short8;

// f32 -> bf16 (round-to-nearest-even), raw-bit version (finite inputs only)
__device__ __forceinline__ unsigned int f2bf(float x) {
  unsigned int u = __builtin_bit_cast(unsigned int, x);
  unsigned int rb = ((u >> 16) & 1u) + 0x7fffu;
  return (u + rb) >> 16;
}
__device__ __forceinline__ unsigned int f2bf2(float lo, float hi) {
  return f2bf(lo) | (f2bf(hi) << 16);
}

// ---- fused prep: blocks 0..1023 -> invnorm (4 rows each); 1024..1535 -> rowdot ----
__global__ __launch_bounds__(256) void k_prep(const float* __restrict__ f,
                                              const float* __restrict__ p,
                                              float* __restrict__ invn,
                                              float* __restrict__ rowdot) {
  if (blockIdx.x < 1024) {
    int lane = threadIdx.x & 63;
    int row = blockIdx.x * 4 + (threadIdx.x >> 6);
    const float* fr = f + (size_t)row * C;
    float ss = 0.f;
#pragma unroll
    for (int i = 0; i < C / 64; ++i) {
      float v = fr[lane + i * 64];
      ss = fmaf(v, v, ss);
    }
#pragma unroll
    for (int m = 32; m >= 1; m >>= 1) ss += __shfl_xor(ss, m, 64);
    if (lane == 0) invn[row] = 1.f / fmaxf(sqrtf(ss), 1e-12f);
  } else {
    int row = (blockIdx.x - 1024) * 8 + (threadIdx.x >> 5);
    int c = threadIdx.x & 31;
    float v = p[(size_t)row * NC + c];
    float t = __expf(v) * v;
#pragma unroll
    for (int m = 16; m >= 1; m >>= 1) t += __shfl_xor(t, m, 64);
    if (c == 0) rowdot[row] = t;
  }
}

// ---- fused pairwise kernel: 128x128 tile per block, both GEMMs via bf16 MFMA ----
// LDS rows padded: As/Bs 64->72 shorts (144B: bank shift 4/row, 2-way = free),
// Es/Ps 32->40 shorts (80B). All fragment reads stay 16B-aligned for ds_read_b128.
__global__ __launch_bounds__(256, 1) void k_pair(
    const float* __restrict__ f, const float* __restrict__ p,
    const float* __restrict__ invn, const float* __restrict__ rowdot,
    float* __restrict__ partials) {
  __shared__ unsigned short As[128 * 72];
  __shared__ unsigned short Bs[128 * 72];
  __shared__ unsigned short Es[128 * 40];
  __shared__ unsigned short Ps[128 * 40];

  const int tid = threadIdx.x;
  const int lane = tid & 63;
  const int wave = tid >> 6;
  const int wy = wave >> 1, wx = wave & 1;
  const int lan = lane & 15, quad = lane >> 4;
  const int n = blockIdx.z;
  const int sBase = blockIdx.y * 128;
  const int lBase = blockIdx.x * 128;

  const float* fA = f + (size_t)(n * S + sBase) * C;
  const float* fB = f + (size_t)(n * S + lBase) * C;
  const float* pS = p + (size_t)(n * S + sBase) * NC;
  const float* pL = p + (size_t)(n * S + lBase) * NC;
  const float* invA = invn + n * S + sBase;
  const float* invB = invn + n * S + lBase;

  f32x4 acc[4][4];
#pragma unroll
  for (int i = 0; i < 4; ++i)
#pragma unroll
    for (int j = 0; j < 4; ++j) acc[i][j] = (f32x4){0.f, 0.f, 0.f, 0.f};

  // stage E = bf16(exp(p_s)) and P = bf16(p_l); covered by first barrier below
#pragma unroll
  for (int it = 0; it < 4; ++it) {
    int idx = tid + it * 256;
    int row = idx >> 3, c4 = idx & 7;
    float4 v = *(const float4*)(pS + row * NC + c4 * 4);
    uint2 ue;
    ue.x = f2bf2(__expf(v.x), __expf(v.y));
    ue.y = f2bf2(__expf(v.z), __expf(v.w));
    *(uint2*)(&Es[row * 40 + c4 * 4]) = ue;
    float4 w = *(const float4*)(pL + row * NC + c4 * 4);
    uint2 up;
    up.x = f2bf2(w.x, w.y);
    up.y = f2bf2(w.z, w.w);
    *(uint2*)(&Ps[row * 40 + c4 * 4]) = up;
  }

  // K loop: 6 chunks of BK=64 over C=384
  for (int kt = 0; kt < 6; ++kt) {
#pragma unroll
    for (int it = 0; it < 8; ++it) {
      int idx = tid + it * 256;
      int row = idx >> 4, c4 = idx & 15;
      float4 a = *(const float4*)(fA + row * C + kt * 64 + c4 * 4);
      float sa = invA[row];
      uint2 ua;
      ua.x = f2bf2(a.x * sa, a.y * sa);
      ua.y = f2bf2(a.z * sa, a.w * sa);
      *(uint2*)(&As[row * 72 + c4 * 4]) = ua;
      float4 b = *(const float4*)(fB + row * C + kt * 64 + c4 * 4);
      float sb = invB[row];
      uint2 ub;
      ub.x = f2bf2(b.x * sb, b.y * sb);
      ub.y = f2bf2(b.z * sb, b.w * sb);
      *(uint2*)(&Bs[row * 72 + c4 * 4]) = ub;
    }
    __syncthreads();
#pragma unroll
    for (int ks = 0; ks < 2; ++ks) {
      short8 af[4], bfr[4];
#pragma unroll
      for (int t = 0; t < 4; ++t)
        af[t] = *(const short8*)(&As[(wy * 64 + t * 16 + lan) * 72 + ks * 32 + quad * 8]);
#pragma unroll
      for (int t = 0; t < 4; ++t)
        bfr[t] = *(const short8*)(&Bs[(wx * 64 + t * 16 + lan) * 72 + ks * 32 + quad * 8]);
#pragma unroll
      for (int i = 0; i < 4; ++i)
#pragma unroll
        for (int j = 0; j < 4; ++j)
          acc[i][j] = __builtin_amdgcn_mfma_f32_16x16x32_bf16(af[i], bfr[j], acc[i][j], 0, 0, 0);
    }
    __syncthreads();  // safe to overwrite As/Bs next iteration
  }

  // EP mini-GEMM: one 16x16x32 MFMA per (i,j) tile (K = NC = 32 exactly)
  f32x4 ep[4][4];
  short8 ea[4], pb[4];
#pragma unroll
  for (int t = 0; t < 4; ++t) {
    ea[t] = *(const short8*)(&Es[(wy * 64 + t * 16 + lan) * 40 + quad * 8]);
    pb[t] = *(const short8*)(&Ps[(wx * 64 + t * 16 + lan) * 40 + quad * 8]);
  }
#pragma unroll
  for (int i = 0; i < 4; ++i)
#pragma unroll
    for (int j = 0; j < 4; ++j) {
      f32x4 z = (f32x4){0.f, 0.f, 0.f, 0.f};
      ep[i][j] = __builtin_amdgcn_mfma_f32_16x16x32_bf16(ea[i], pb[j], z, 0, 0, 0);
    }

  // epilogue: C/D layout col=lane&15, row=quad*4+reg
  float pos_s = 0.f, neg_s = 0.f, posc = 0.f, negc = 0.f;
#pragma unroll
  for (int i = 0; i < 4; ++i) {
    float rd[4];
    int gs = n * S + sBase + wy * 64 + i * 16 + quad * 4;
#pragma unroll
    for (int r = 0; r < 4; ++r) rd[r] = rowdot[gs + r];
#pragma unroll
    for (int j = 0; j < 4; ++j) {
#pragma unroll
      for (int r = 0; r < 4; ++r) {
        float fc = acc[i][j][r] - SHIFT;
        float pc = rd[r] - ep[i][j][r];
        if (fc > 0.f) {
          pos_s = fmaf(fc, pc, pos_s);
          posc += 1.f;
        } else if (fc < 0.f) {
          neg_s = fmaf(fc, pc, neg_s);
          negc += 1.f;
        }
      }
    }
  }
#pragma unroll
  for (int m = 32; m >= 1; m >>= 1) {
    pos_s += __shfl_xor(pos_s, m, 64);
    neg_s += __shfl_xor(neg_s, m, 64);
    posc += __shfl_xor(posc, m, 64);
    negc += __shfl_xor(negc, m, 64);
  }
  // no atomics: one float4 partial per wave (1024 total), reduced in k_final
  if (lane == 0) {
    int bid = (blockIdx.z * 8 + blockIdx.y) * 8 + blockIdx.x;
    *(float4*)(&partials[(bid * 4 + wave) * 4]) = make_float4(pos_s, neg_s, posc, negc);
  }
}

__global__ __launch_bounds__(256) void k_final(const float* __restrict__ partials,
                                               float* __restrict__ out) {
  int tid = threadIdx.x;
  float4 s = make_float4(0.f, 0.f, 0.f, 0.f);
#pragma unroll
  for (int i = 0; i < 4; ++i) {
    float4 v = ((const float4*)partials)[tid + i * 256];
    s.x += v.x;
    s.y += v.y;
    s.z += v.z;
    s.w += v.w;
  }
#pragma unroll
  for (int m = 32; m >= 1; m >>= 1) {
    s.x += __shfl_xor(s.x, m, 64);
    s.y += __shfl_xor(s.y, m, 64);
    s.z += __shfl_xor(s.z, m, 64);
    s.w += __shfl_xor(s.w, m, 64);
  }
  __shared__ float4 red[4];
  if ((tid & 63) == 0) red[tid >> 6] = s;
  __syncthreads();
  if (tid == 0) {
    float4 t = red[0];
#pragma unroll
    for (int w = 1; w < 4; ++w) {
      t.x += red[w].x;
      t.y += red[w].y;
      t.z += red[w].z;
      t.w += red[w].w;
    }
    out[0] = t.x / t.z;
    out[1] = t.y / t.w;
  }
}

extern "C" void kernel_launch(void* const* d_in, const int* in_sizes, int n_in,
                              void* d_out, int out_size, void* d_ws, size_t ws_size,
                              hipStream_t stream) {
  const float* f = (const float*)d_in[0];  // feats [4,32,32,384] f32
  const float* p = (const float*)d_in[1];  // p_class [4,32,32,32] f32 (log-probs)
  float* out = (float*)d_out;              // [pos, neg]
  float* ws = (float*)d_ws;
  float* invn = ws;              // 4096 floats
  float* rowdot = ws + 4096;     // 4096 floats
  float* partials = ws + 8192;   // 1024 waves * 4 floats (fully overwritten each call)

  k_prep<<<dim3(1536), dim3(256), 0, stream>>>(f, p, invn, rowdot);
  k_pair<<<dim3(8, 8, 4), dim3(256), 0, stream>>>(f, p, invn, rowdot, partials);
  k_final<<<dim3(1), dim3(256), 0, stream>>>(partials, out);
}

// Round 4
// 74.837 us; speedup vs baseline: 1.7716x; 1.0747x over previous
//
#include <hip/hip_runtime.h>
#include <hip/hip_bf16.h>

#define S 1024
#define C 384
#define NC 32
#define SHIFT 0.3f

typedef __attribute__((ext_vector_type(4))) float f32x4;
typedef __attribute__((ext_vector_type(8))) short short8;

// f32 -> bf16 (round-to-nearest-even), raw-bit version (finite inputs only)
__device__ __forceinline__ unsigned int f2bf(float x) {
  unsigned int u = __builtin_bit_cast(unsigned int, x);
  unsigned int rb = ((u >> 16) & 1u) + 0x7fffu;
  return (u + rb) >> 16;
}
__device__ __forceinline__ unsigned int f2bf2(float lo, float hi) {
  return f2bf(lo) | (f2bf(hi) << 16);
}

// async global->LDS, 16B per lane; LDS dest is wave-uniform base + lane*16
__device__ __forceinline__ void gld16(void* lds, const void* g) {
  __builtin_amdgcn_global_load_lds(
      (const __attribute__((address_space(1))) void*)g,
      (__attribute__((address_space(3))) void*)lds, 16, 0, 0);
}

// ---- prep: normalize f -> bf16 fnb; exp(p)/p -> bf16 Eb/Pb; rowdot ----
__global__ __launch_bounds__(256) void k_prep(const float* __restrict__ f,
                                              const float* __restrict__ p,
                                              unsigned int* __restrict__ fnb,
                                              unsigned int* __restrict__ Eb,
                                              unsigned int* __restrict__ Pb,
                                              float* __restrict__ rowdot) {
  if (blockIdx.x < 1024) {
    // one wave per feat row: sum squares, scale, pack bf16
    int lane = threadIdx.x & 63;
    int row = blockIdx.x * 4 + (threadIdx.x >> 6);
    const float* fr = f + (size_t)row * C;
    float2 v[3];
    float ss = 0.f;
#pragma unroll
    for (int j = 0; j < 3; ++j) {
      v[j] = *(const float2*)(fr + 2 * lane + 128 * j);
      ss = fmaf(v[j].x, v[j].x, fmaf(v[j].y, v[j].y, ss));
    }
#pragma unroll
    for (int m = 32; m >= 1; m >>= 1) ss += __shfl_xor(ss, m, 64);
    float s = 1.f / fmaxf(sqrtf(ss), 1e-12f);
    unsigned int* outr = fnb + (size_t)row * (C / 2);
#pragma unroll
    for (int j = 0; j < 3; ++j) outr[lane + 64 * j] = f2bf2(v[j].x * s, v[j].y * s);
  } else {
    // 4 threads per p-row: pack exp(p) and p to bf16, reduce rowdot
    int t = (blockIdx.x - 1024) * 256 + threadIdx.x;  // [0, 16384)
    int r = t >> 2, q = t & 3;
    const float* pr = p + (size_t)r * NC + q * 8;
    float4 a = *(const float4*)pr;
    float4 b = *(const float4*)(pr + 4);
    float ea0 = __expf(a.x), ea1 = __expf(a.y), ea2 = __expf(a.z), ea3 = __expf(a.w);
    float eb0 = __expf(b.x), eb1 = __expf(b.y), eb2 = __expf(b.z), eb3 = __expf(b.w);
    uint4 ue = make_uint4(f2bf2(ea0, ea1), f2bf2(ea2, ea3), f2bf2(eb0, eb1), f2bf2(eb2, eb3));
    uint4 up = make_uint4(f2bf2(a.x, a.y), f2bf2(a.z, a.w), f2bf2(b.x, b.y), f2bf2(b.z, b.w));
    *(uint4*)(Eb + r * 16 + q * 4) = ue;
    *(uint4*)(Pb + r * 16 + q * 4) = up;
    float s = ea0 * a.x + ea1 * a.y + ea2 * a.z + ea3 * a.w +
              eb0 * b.x + eb1 * b.y + eb2 * b.z + eb3 * b.w;
    s += __shfl_xor(s, 1, 64);
    s += __shfl_xor(s, 2, 64);
    if (q == 0) rowdot[r] = s;
  }
}

// ---- pairwise: 128x128 tile, A/B staged via global_load_lds + XOR swizzle ----
// LDS slot (row, c) holds global 16B-chunk c ^ (row&7); fragment reads undo it.
// 2 lanes/bank residual aliasing = free (m136).
__global__ __launch_bounds__(256, 1) void k_pair(
    const unsigned short* __restrict__ fnb, const unsigned short* __restrict__ Eb,
    const unsigned short* __restrict__ Pb, const float* __restrict__ rowdot,
    float* __restrict__ partials) {
  __shared__ unsigned short As[128 * 64];
  __shared__ unsigned short Bs[128 * 64];
  __shared__ unsigned short Es[128 * 40];  // padded (+8) for conflict-free reads
  __shared__ unsigned short Ps[128 * 40];

  const int tid = threadIdx.x;
  const int lane = tid & 63;
  const int wave = tid >> 6;
  const int wy = wave >> 1, wx = wave & 1;
  const int lan = lane & 15, quad = lane >> 4;
  const int n = blockIdx.z;
  const int sBase = blockIdx.y * 128;
  const int lBase = blockIdx.x * 128;

  // per-lane swizzled global source addresses for A/B staging
  const int r8 = lane >> 3, c8 = lane & 7;
  const char* gA = (const char*)fnb +
                   ((size_t)(n * S + sBase + 32 * wave + r8)) * 768 + ((c8 ^ r8) << 4);
  const char* gB = (const char*)fnb +
                   ((size_t)(n * S + lBase + 32 * wave + r8)) * 768 + ((c8 ^ r8) << 4);
  char* lA = (char*)As + (32 * wave) * 128;
  char* lB = (char*)Bs + (32 * wave) * 128;

  f32x4 acc[4][4];
#pragma unroll
  for (int i = 0; i < 4; ++i)
#pragma unroll
    for (int j = 0; j < 4; ++j) acc[i][j] = (f32x4){0.f, 0.f, 0.f, 0.f};

  // stage E = bf16(exp(p_s)), P = bf16(p_l) once (covered by first barrier)
#pragma unroll
  for (int it = 0; it < 2; ++it) {
    int idx = tid + it * 256;
    int row = idx >> 2, q = idx & 3;
    *(uint4*)(&Es[row * 40 + q * 8]) =
        *(const uint4*)(Eb + (size_t)(n * S + sBase + row) * 32 + q * 8);
    *(uint4*)(&Ps[row * 40 + q * 8]) =
        *(const uint4*)(Pb + (size_t)(n * S + lBase + row) * 32 + q * 8);
  }

  // K loop: 6 chunks of BK=64 over C=384; staging = 8 global_load_lds/wave
  for (int kt = 0; kt < 6; ++kt) {
#pragma unroll
    for (int i = 0; i < 4; ++i) {
      gld16(lA + i * 1024, gA + i * 6144 + kt * 128);
      gld16(lB + i * 1024, gB + i * 6144 + kt * 128);
    }
    __syncthreads();
#pragma unroll
    for (int ks = 0; ks < 2; ++ks) {
      short8 af[4], bfr[4];
#pragma unroll
      for (int t = 0; t < 4; ++t) {
        int rowA = wy * 64 + t * 16 + lan;
        af[t] = *(const short8*)((const char*)As + rowA * 128 +
                                 ((((ks << 2) | quad) ^ (lan & 7)) << 4));
      }
#pragma unroll
      for (int t = 0; t < 4; ++t) {
        int rowB = wx * 64 + t * 16 + lan;
        bfr[t] = *(const short8*)((const char*)Bs + rowB * 128 +
                                  ((((ks << 2) | quad) ^ (lan & 7)) << 4));
      }
#pragma unroll
      for (int i = 0; i < 4; ++i)
#pragma unroll
        for (int j = 0; j < 4; ++j)
          acc[i][j] = __builtin_amdgcn_mfma_f32_16x16x32_bf16(af[i], bfr[j], acc[i][j], 0, 0, 0);
    }
    __syncthreads();
  }

  // epilogue: EP mini-GEMM (K=NC=32, one MFMA per tile) fused with reduction
  // C/D layout col=lane&15, row=quad*4+reg
  short8 ea[4], pb[4];
#pragma unroll
  for (int t = 0; t < 4; ++t) {
    ea[t] = *(const short8*)(&Es[(wy * 64 + t * 16 + lan) * 40 + quad * 8]);
    pb[t] = *(const short8*)(&Ps[(wx * 64 + t * 16 + lan) * 40 + quad * 8]);
  }
  float pos_s = 0.f, neg_s = 0.f, posc = 0.f, negc = 0.f;
#pragma unroll
  for (int i = 0; i < 4; ++i) {
    float rd[4];
    int gs = n * S + sBase + wy * 64 + i * 16 + quad * 4;
#pragma unroll
    for (int r = 0; r < 4; ++r) rd[r] = rowdot[gs + r];
#pragma unroll
    for (int j = 0; j < 4; ++j) {
      f32x4 z = (f32x4){0.f, 0.f, 0.f, 0.f};
      f32x4 ep = __builtin_amdgcn_mfma_f32_16x16x32_bf16(ea[i], pb[j], z, 0, 0, 0);
#pragma unroll
      for (int r = 0; r < 4; ++r) {
        float fc = acc[i][j][r] - SHIFT;
        float pc = rd[r] - ep[r];
        if (fc > 0.f) {
          pos_s = fmaf(fc, pc, pos_s);
          posc += 1.f;
        } else if (fc < 0.f) {
          neg_s = fmaf(fc, pc, neg_s);
          negc += 1.f;
        }
      }
    }
  }
#pragma unroll
  for (int m = 32; m >= 1; m >>= 1) {
    pos_s += __shfl_xor(pos_s, m, 64);
    neg_s += __shfl_xor(neg_s, m, 64);
    posc += __shfl_xor(posc, m, 64);
    negc += __shfl_xor(negc, m, 64);
  }
  if (lane == 0) {
    int bid = (blockIdx.z * 8 + blockIdx.y) * 8 + blockIdx.x;
    *(float4*)(&partials[(bid * 4 + wave) * 4]) = make_float4(pos_s, neg_s, posc, negc);
  }
}

__global__ __launch_bounds__(256) void k_final(const float* __restrict__ partials,
                                               float* __restrict__ out) {
  int tid = threadIdx.x;
  float4 s = make_float4(0.f, 0.f, 0.f, 0.f);
#pragma unroll
  for (int i = 0; i < 4; ++i) {
    float4 v = ((const float4*)partials)[tid + i * 256];
    s.x += v.x;
    s.y += v.y;
    s.z += v.z;
    s.w += v.w;
  }
#pragma unroll
  for (int m = 32; m >= 1; m >>= 1) {
    s.x += __shfl_xor(s.x, m, 64);
    s.y += __shfl_xor(s.y, m, 64);
    s.z += __shfl_xor(s.z, m, 64);
    s.w += __shfl_xor(s.w, m, 64);
  }
  __shared__ float4 red[4];
  if ((tid & 63) == 0) red[tid >> 6] = s;
  __syncthreads();
  if (tid == 0) {
    float4 t = red[0];
#pragma unroll
    for (int w = 1; w < 4; ++w) {
      t.x += red[w].x;
      t.y += red[w].y;
      t.z += red[w].z;
      t.w += red[w].w;
    }
    out[0] = t.x / t.z;
    out[1] = t.y / t.w;
  }
}

extern "C" void kernel_launch(void* const* d_in, const int* in_sizes, int n_in,
                              void* d_out, int out_size, void* d_ws, size_t ws_size,
                              hipStream_t stream) {
  const float* f = (const float*)d_in[0];  // feats [4,32,32,384] f32
  const float* p = (const float*)d_in[1];  // p_class [4,32,32,32] f32 (log-probs)
  float* out = (float*)d_out;              // [pos, neg]
  float* ws = (float*)d_ws;
  // ws layout (floats): rowdot @0 (4096) | partials @4096 (4096) |
  // fnb @8192 (4096x384 bf16 = 786432 f) | Eb @794624 (65536 f) | Pb @860160 (65536 f)
  float* rowdot = ws;
  float* partials = ws + 4096;
  unsigned int* fnb = (unsigned int*)(ws + 8192);
  unsigned int* Eb = (unsigned int*)(ws + 794624);
  unsigned int* Pb = (unsigned int*)(ws + 860160);

  k_prep<<<dim3(1088), dim3(256), 0, stream>>>(f, p, fnb, Eb, Pb, rowdot);
  k_pair<<<dim3(8, 8, 4), dim3(256), 0, stream>>>((const unsigned short*)fnb,
                                                  (const unsigned short*)Eb,
                                                  (const unsigned short*)Pb, rowdot, partials);
  k_final<<<dim3(1), dim3(256), 0, stream>>>(partials, out);
}

// Round 5
// 71.393 us; speedup vs baseline: 1.8571x; 1.0482x over previous
//
#include <hip/hip_runtime.h>
#include <hip/hip_bf16.h>

#define S 1024
#define C 384
#define NC 32
#define SHIFT 0.3f

typedef __attribute__((ext_vector_type(4))) float f32x4;
typedef __attribute__((ext_vector_type(8))) short short8;

// f32 -> bf16 (round-to-nearest-even), raw-bit version (finite inputs only)
__device__ __forceinline__ unsigned int f2bf(float x) {
  unsigned int u = __builtin_bit_cast(unsigned int, x);
  unsigned int rb = ((u >> 16) & 1u) + 0x7fffu;
  return (u + rb) >> 16;
}
__device__ __forceinline__ unsigned int f2bf2(float lo, float hi) {
  return f2bf(lo) | (f2bf(hi) << 16);
}

// async global->LDS, 16B per lane; LDS dest is wave-uniform base + lane*16
__device__ __forceinline__ void gld16(void* lds, const void* g) {
  __builtin_amdgcn_global_load_lds(
      (const __attribute__((address_space(1))) void*)g,
      (__attribute__((address_space(3))) void*)lds, 16, 0, 0);
}

// ---- prep: normalize f -> bf16 fnb; exp(p)/p -> bf16 Eb/Pb; rowdot ----
__global__ __launch_bounds__(256) void k_prep(const float* __restrict__ f,
                                              const float* __restrict__ p,
                                              unsigned int* __restrict__ fnb,
                                              unsigned int* __restrict__ Eb,
                                              unsigned int* __restrict__ Pb,
                                              float* __restrict__ rowdot) {
  if (blockIdx.x < 1024) {
    // one wave per feat row: sum squares, scale, pack bf16
    int lane = threadIdx.x & 63;
    int row = blockIdx.x * 4 + (threadIdx.x >> 6);
    const float* fr = f + (size_t)row * C;
    float2 v[3];
    float ss = 0.f;
#pragma unroll
    for (int j = 0; j < 3; ++j) {
      v[j] = *(const float2*)(fr + 2 * lane + 128 * j);
      ss = fmaf(v[j].x, v[j].x, fmaf(v[j].y, v[j].y, ss));
    }
#pragma unroll
    for (int m = 32; m >= 1; m >>= 1) ss += __shfl_xor(ss, m, 64);
    float s = 1.f / fmaxf(sqrtf(ss), 1e-12f);
    unsigned int* outr = fnb + (size_t)row * (C / 2);
#pragma unroll
    for (int j = 0; j < 3; ++j) outr[lane + 64 * j] = f2bf2(v[j].x * s, v[j].y * s);
  } else {
    // 4 threads per p-row: pack exp(p) and p to bf16, reduce rowdot
    int t = (blockIdx.x - 1024) * 256 + threadIdx.x;  // [0, 16384)
    int r = t >> 2, q = t & 3;
    const float* pr = p + (size_t)r * NC + q * 8;
    float4 a = *(const float4*)pr;
    float4 b = *(const float4*)(pr + 4);
    float ea0 = __expf(a.x), ea1 = __expf(a.y), ea2 = __expf(a.z), ea3 = __expf(a.w);
    float eb0 = __expf(b.x), eb1 = __expf(b.y), eb2 = __expf(b.z), eb3 = __expf(b.w);
    uint4 ue = make_uint4(f2bf2(ea0, ea1), f2bf2(ea2, ea3), f2bf2(eb0, eb1), f2bf2(eb2, eb3));
    uint4 up = make_uint4(f2bf2(a.x, a.y), f2bf2(a.z, a.w), f2bf2(b.x, b.y), f2bf2(b.z, b.w));
    *(uint4*)(Eb + r * 16 + q * 4) = ue;
    *(uint4*)(Pb + r * 16 + q * 4) = up;
    float s = ea0 * a.x + ea1 * a.y + ea2 * a.z + ea3 * a.w +
              eb0 * b.x + eb1 * b.y + eb2 * b.z + eb3 * b.w;
    s += __shfl_xor(s, 1, 64);
    s += __shfl_xor(s, 2, 64);
    if (q == 0) rowdot[r] = s;
  }
}

// ---- pairwise: 64x128 tile (512 blocks = 2/CU), global_load_lds + XOR swizzle ----
// wave w computes output cols [32w,32w+32): acc[4][2]; A-fragments shared by all waves.
// LDS slot (row, c) holds global 16B-chunk c ^ (row&7); fragment reads undo it.
__global__ __launch_bounds__(256) void k_pair(
    const unsigned short* __restrict__ fnb, const unsigned short* __restrict__ Eb,
    const unsigned short* __restrict__ Pb, const float* __restrict__ rowdot,
    float* __restrict__ partials) {
  __shared__ unsigned short As[64 * 64];
  __shared__ unsigned short Bs[128 * 64];
  __shared__ unsigned short Es[64 * 40];   // padded (+8) rows for conflict-free reads
  __shared__ unsigned short Ps[128 * 40];

  const int tid = threadIdx.x;
  const int lane = tid & 63;
  const int wave = tid >> 6;
  const int lan = lane & 15, quad = lane >> 4;
  const int n = blockIdx.z;
  const int sBase = blockIdx.y * 64;
  const int lBase = blockIdx.x * 128;

  // per-lane swizzled global source addresses for A/B staging
  const int r8 = lane >> 3, c8 = lane & 7;
  const char* gA = (const char*)fnb +
                   ((size_t)(n * S + sBase + 16 * wave + r8)) * 768 + ((c8 ^ r8) << 4);
  const char* gB = (const char*)fnb +
                   ((size_t)(n * S + lBase + 32 * wave + r8)) * 768 + ((c8 ^ r8) << 4);
  char* lA = (char*)As + (16 * wave) * 128;
  char* lB = (char*)Bs + (32 * wave) * 128;

  f32x4 acc[4][2];
#pragma unroll
  for (int i = 0; i < 4; ++i)
#pragma unroll
    for (int j = 0; j < 2; ++j) acc[i][j] = (f32x4){0.f, 0.f, 0.f, 0.f};

  // stage E = bf16(exp(p_s)) (64 rows), P = bf16(p_l) (128 rows); covered by 1st barrier
  {
    int row = tid >> 2, q = tid & 3;
    *(uint4*)(&Es[row * 40 + q * 8]) =
        *(const uint4*)(Eb + (size_t)(n * S + sBase + row) * 32 + q * 8);
  }
#pragma unroll
  for (int it = 0; it < 2; ++it) {
    int idx = tid + it * 256;
    int row = idx >> 2, q = idx & 3;
    *(uint4*)(&Ps[row * 40 + q * 8]) =
        *(const uint4*)(Pb + (size_t)(n * S + lBase + row) * 32 + q * 8);
  }

  // K loop: 6 chunks of BK=64 over C=384; staging = 6 global_load_lds/wave
  for (int kt = 0; kt < 6; ++kt) {
#pragma unroll
    for (int i = 0; i < 2; ++i) gld16(lA + i * 1024, gA + i * 6144 + kt * 128);
#pragma unroll
    for (int i = 0; i < 4; ++i) gld16(lB + i * 1024, gB + i * 6144 + kt * 128);
    __syncthreads();
#pragma unroll
    for (int ks = 0; ks < 2; ++ks) {
      short8 af[4], bfr[2];
#pragma unroll
      for (int t = 0; t < 4; ++t) {
        int rowA = t * 16 + lan;
        af[t] = *(const short8*)((const char*)As + rowA * 128 +
                                 ((((ks << 2) | quad) ^ (lan & 7)) << 4));
      }
#pragma unroll
      for (int t = 0; t < 2; ++t) {
        int rowB = wave * 32 + t * 16 + lan;
        bfr[t] = *(const short8*)((const char*)Bs + rowB * 128 +
                                  ((((ks << 2) | quad) ^ (lan & 7)) << 4));
      }
#pragma unroll
      for (int i = 0; i < 4; ++i)
#pragma unroll
        for (int j = 0; j < 2; ++j)
          acc[i][j] = __builtin_amdgcn_mfma_f32_16x16x32_bf16(af[i], bfr[j], acc[i][j], 0, 0, 0);
    }
    __syncthreads();
  }

  // epilogue: EP mini-GEMM (K=NC=32) fused with masked reduction
  // C/D layout col=lane&15, row=quad*4+reg
  short8 ea[4], pb[2];
#pragma unroll
  for (int t = 0; t < 4; ++t)
    ea[t] = *(const short8*)(&Es[(t * 16 + lan) * 40 + quad * 8]);
#pragma unroll
  for (int t = 0; t < 2; ++t)
    pb[t] = *(const short8*)(&Ps[(wave * 32 + t * 16 + lan) * 40 + quad * 8]);

  float pos_s = 0.f, neg_s = 0.f, posc = 0.f, negc = 0.f;
#pragma unroll
  for (int i = 0; i < 4; ++i) {
    float rd[4];
    int gs = n * S + sBase + i * 16 + quad * 4;
#pragma unroll
    for (int r = 0; r < 4; ++r) rd[r] = rowdot[gs + r];
#pragma unroll
    for (int j = 0; j < 2; ++j) {
      f32x4 z = (f32x4){0.f, 0.f, 0.f, 0.f};
      f32x4 ep = __builtin_amdgcn_mfma_f32_16x16x32_bf16(ea[i], pb[j], z, 0, 0, 0);
#pragma unroll
      for (int r = 0; r < 4; ++r) {
        float fc = acc[i][j][r] - SHIFT;
        float pc = rd[r] - ep[r];
        if (fc > 0.f) {
          pos_s = fmaf(fc, pc, pos_s);
          posc += 1.f;
        } else if (fc < 0.f) {
          neg_s = fmaf(fc, pc, neg_s);
          negc += 1.f;
        }
      }
    }
  }
#pragma unroll
  for (int m = 32; m >= 1; m >>= 1) {
    pos_s += __shfl_xor(pos_s, m, 64);
    neg_s += __shfl_xor(neg_s, m, 64);
    posc += __shfl_xor(posc, m, 64);
    negc += __shfl_xor(negc, m, 64);
  }
  if (lane == 0) {
    int bid = (blockIdx.z * 16 + blockIdx.y) * 8 + blockIdx.x;
    *(float4*)(&partials[(bid * 4 + wave) * 4]) = make_float4(pos_s, neg_s, posc, negc);
  }
}

__global__ __launch_bounds__(256) void k_final(const float* __restrict__ partials,
                                               float* __restrict__ out) {
  int tid = threadIdx.x;
  float4 s = make_float4(0.f, 0.f, 0.f, 0.f);
#pragma unroll
  for (int i = 0; i < 8; ++i) {
    float4 v = ((const float4*)partials)[tid + i * 256];
    s.x += v.x;
    s.y += v.y;
    s.z += v.z;
    s.w += v.w;
  }
#pragma unroll
  for (int m = 32; m >= 1; m >>= 1) {
    s.x += __shfl_xor(s.x, m, 64);
    s.y += __shfl_xor(s.y, m, 64);
    s.z += __shfl_xor(s.z, m, 64);
    s.w += __shfl_xor(s.w, m, 64);
  }
  __shared__ float4 red[4];
  if ((tid & 63) == 0) red[tid >> 6] = s;
  __syncthreads();
  if (tid == 0) {
    float4 t = red[0];
#pragma unroll
    for (int w = 1; w < 4; ++w) {
      t.x += red[w].x;
      t.y += red[w].y;
      t.z += red[w].z;
      t.w += red[w].w;
    }
    out[0] = t.x / t.z;
    out[1] = t.y / t.w;
  }
}

extern "C" void kernel_launch(void* const* d_in, const int* in_sizes, int n_in,
                              void* d_out, int out_size, void* d_ws, size_t ws_size,
                              hipStream_t stream) {
  const float* f = (const float*)d_in[0];  // feats [4,32,32,384] f32
  const float* p = (const float*)d_in[1];  // p_class [4,32,32,32] f32 (log-probs)
  float* out = (float*)d_out;              // [pos, neg]
  float* ws = (float*)d_ws;
  // ws layout (floats): rowdot @0 (4096) | partials @4096 (8192 = 2048 waves x4) |
  // fnb @12288 (786432) | Eb @798720 (65536) | Pb @864256 (65536)
  float* rowdot = ws;
  float* partials = ws + 4096;
  unsigned int* fnb = (unsigned int*)(ws + 12288);
  unsigned int* Eb = (unsigned int*)(ws + 798720);
  unsigned int* Pb = (unsigned int*)(ws + 864256);

  k_prep<<<dim3(1088), dim3(256), 0, stream>>>(f, p, fnb, Eb, Pb, rowdot);
  k_pair<<<dim3(8, 16, 4), dim3(256), 0, stream>>>((const unsigned short*)fnb,
                                                   (const unsigned short*)Eb,
                                                   (const unsigned short*)Pb, rowdot, partials);
  k_final<<<dim3(1), dim3(256), 0, stream>>>(partials, out);
}